// Round 4
// baseline (2624.162 us; speedup 1.0000x reference)
//
#include <hip/hip_runtime.h>
#include <stdint.h>

typedef unsigned short u16;
typedef unsigned int u32;
typedef __attribute__((ext_vector_type(4))) float f32x4;
typedef __attribute__((ext_vector_type(8))) short bf16x8;
typedef __attribute__((ext_vector_type(8))) u16 u16x8;

#define MROWS 16384
#define NP    2560   // padded N / K for 2500-dims
#define K1P   2688   // padded K for 2675 (train_feat / W1_self)

// ---------------- helpers ----------------

__device__ __forceinline__ u16 f2bf(float f) {
    u32 u = __float_as_uint(f);
    u32 r = (u + 0x7fffu + ((u >> 16) & 1u)) >> 16;   // round-to-nearest-even
    return (u16)r;
}

__device__ __forceinline__ void async_ld16(const void* g, void* l) {
    __builtin_amdgcn_global_load_lds((const __attribute__((address_space(1))) u32*)g,
                                     (__attribute__((address_space(3))) u32*)l,
                                     16, 0, 0);
}

// ---------------- prep kernels ----------------

// Scalar-load row convert (for rows NOT 16B-aligned, e.g. stride 2675 fp32).
// Lane-interleaved scalar loads (coalesced) + scalar u16 stores (coalesced 128B).
__global__ void cvt_pad_s(const float* __restrict__ src, u16* __restrict__ dst,
                          int R, int C, int Cp) {
    const int r = blockIdx.x;
    u16* drow = dst + (size_t)r * Cp;
    if (r < R) {
        const float* srow = src + (size_t)r * C;
        for (int c = threadIdx.x; c < Cp; c += blockDim.x)
            drow[c] = (c < C) ? f2bf(srow[c]) : (u16)0;
    } else {
        for (int c = threadIdx.x; c < Cp; c += blockDim.x) drow[c] = 0;
    }
}

// Vector row convert: REQUIRES src rows 16B-aligned (C*4 % 16 == 0 and base 16B).
__device__ __forceinline__ void cvt_row_vec(const float* __restrict__ srow,
                                            u16* __restrict__ drow,
                                            bool valid, int C, int Cp) {
    for (int c = threadIdx.x * 8; c < Cp; c += blockDim.x * 8) {
        u16x8 o;
        if (valid && c + 8 <= C) {
            float4 a = *(const float4*)(srow + c);       // 16B aligned
            float4 b = *(const float4*)(srow + c + 4);
            o[0]=f2bf(a.x); o[1]=f2bf(a.y); o[2]=f2bf(a.z); o[3]=f2bf(a.w);
            o[4]=f2bf(b.x); o[5]=f2bf(b.y); o[6]=f2bf(b.z); o[7]=f2bf(b.w);
        } else {
            #pragma unroll
            for (int j = 0; j < 8; ++j)
                o[j] = (valid && c + j < C) ? f2bf(srow[c + j]) : (u16)0;
        }
        *(u16x8*)(drow + c) = o;                         // dst rows 16B aligned
    }
}

// 4 square 2500x2500 -> 2560x2560 weights in one launch (rows 10000B = 16B-aligned)
__global__ void cvt_pad4(const float* s0, const float* s1, const float* s2, const float* s3,
                         u16* d0, u16* d1, u16* d2, u16* d3) {
    const int m = blockIdx.y;
    const float* s = (m == 0) ? s0 : (m == 1) ? s1 : (m == 2) ? s2 : s3;
    u16*        d = (m == 0) ? d0 : (m == 1) ? d1 : (m == 2) ? d2 : d3;
    const int r = blockIdx.x;
    cvt_row_vec(s + (size_t)r * 2500, d + (size_t)r * NP, r < 2500, 2500, NP);
}

// Wc2 [16,2500] (rows 16B-aligned) -> [16,NP]
__global__ void cvt_pad_wc2(const float* __restrict__ src, u16* __restrict__ dst) {
    const int r = blockIdx.x;
    cvt_row_vec(src + (size_t)r * 2500, dst + (size_t)r * NP, true, 2500, NP);
}

// 3 bias vectors padded in one launch
__global__ void pad_vec3(const float* b1, const float* b2, const float* b3,
                         float* o1, float* o2, float* o3) {
    int i = blockIdx.x * blockDim.x + threadIdx.x;
    int which = i / NP, off = i % NP;
    const float* s = (which == 0) ? b1 : (which == 1) ? b2 : b3;
    float*       o = (which == 0) ? o1 : (which == 1) ? o2 : o3;
    if (which < 3) o[off] = (off < 2500) ? s[off] : 0.f;
}

// gene_feat [2500,2500] fp32 -> dst [NP,NP] bf16, dst[n][k] = src[k][n]
__global__ void transpose_cvt(const float* __restrict__ src, u16* __restrict__ dst) {
    __shared__ float t[64][65];
    const int n0 = blockIdx.x * 64;
    const int k0 = blockIdx.y * 64;
    const int tid = threadIdx.x;
    const int ln = tid & 63, kq = tid >> 6;      // load: lanes sweep n (coalesced)
    #pragma unroll 4
    for (int i = 0; i < 16; ++i) {
        int kl = i * 4 + kq;
        int k = k0 + kl, n = n0 + ln;
        t[kl][ln] = (k < 2500 && n < 2500) ? src[(size_t)k * 2500 + n] : 0.f;
    }
    __syncthreads();
    const int c = tid & 7, rr = tid >> 3;        // store: ushort8 per thread
    #pragma unroll
    for (int p = 0; p < 2; ++p) {
        int r = rr + p * 32;
        u16x8 o;
        #pragma unroll
        for (int j = 0; j < 8; ++j) o[j] = f2bf(t[c * 8 + j][r]);
        *(u16x8*)(dst + (size_t)(n0 + r) * NP + k0 + c * 8) = o;
    }
}

// u32 counts + fused dst-degree histogram (all standard device-scope atomics)
__global__ void build_counts_u32(const int* __restrict__ esrc, const int* __restrict__ edst,
                                 int E, u32* __restrict__ acnt, u32* __restrict__ hist) {
    int i = blockIdx.x * blockDim.x + threadIdx.x;
    if (i >= E) return;
    int d = edst[i];
    atomicAdd(&acnt[(size_t)d * NP + esrc[i]], 1u);
    atomicAdd(&hist[d], 1u);
}

// u32 counts -> bf16, flat, 16B loads/stores (exact: counts are small ints)
__global__ void cvt_counts_v(const u32* __restrict__ a, u16* __restrict__ b) {
    size_t i = ((size_t)blockIdx.x * 256 + threadIdx.x) * 8;
    uint4 x = *(const uint4*)(a + i);
    uint4 y = *(const uint4*)(a + i + 4);
    u16x8 o;
    o[0]=f2bf((float)x.x); o[1]=f2bf((float)x.y); o[2]=f2bf((float)x.z); o[3]=f2bf((float)x.w);
    o[4]=f2bf((float)y.x); o[5]=f2bf((float)y.y); o[6]=f2bf((float)y.z); o[7]=f2bf((float)y.w);
    *(u16x8*)(b + i) = o;
}

__global__ void rdeg_from_hist(const u32* __restrict__ hist, float* __restrict__ rdeg) {
    int i = blockIdx.x * blockDim.x + threadIdx.x;
    if (i < MROWS) rdeg[i] = 1.f / fmaxf((float)hist[i], 1.f);
}

// ---------------- main MFMA GEMM (unchanged from R2, verified) ----------------
// C[M,N](bf16) = epilogue( A1[M,K1] @ B1[N,K1]^T (+ A2[M,K2] @ B2[N,K2]^T) )
// BIAS_RELU: epilogue = relu(acc + bias[col]); else: acc * rdeg[row]
// XOR-swizzled LDS (swizzle on global source addr; global_load_lds forces
// dst = base + lane*16) -> zero bank conflicts (verified R2).
template<bool PAIR2, bool BIAS_RELU>
__global__ __launch_bounds__(256) void gemm_bt(
    const u16* __restrict__ A1, const u16* __restrict__ B1, int K1,
    const u16* __restrict__ A2, const u16* __restrict__ B2, int K2,
    const float* __restrict__ epi, u16* __restrict__ C, int N)
{
    __shared__ __align__(16) u16 lA[128 * 64];
    __shared__ __align__(16) u16 lB[128 * 64];

    const int tid  = threadIdx.x;
    const int bm   = blockIdx.y * 128;
    const int bn   = blockIdx.x * 128;
    const int wave = tid >> 6;
    const int lane = tid & 63;
    const int wr   = (wave >> 1) << 6;
    const int wc   = (wave & 1) << 6;
    const int lrow = lane & 15;
    const int lkq  = lane >> 4;
    const int xr   = lrow & 7;

    const int sr  = tid >> 3;
    const int sc  = (tid & 7) << 3;
    const int gsw = (((tid & 7) ^ (sr & 7)) << 3);

    f32x4 acc[4][4] = {};

    #pragma unroll
    for (int pair = 0; pair < (PAIR2 ? 2 : 1); ++pair) {
        const u16* A = (PAIR2 && pair) ? A2 : A1;
        const u16* B = (PAIR2 && pair) ? B2 : B1;
        const int  K = (PAIR2 && pair) ? K2 : K1;
        const u16* gA = A + (size_t)(bm + sr) * K + gsw;
        const u16* gB = B + (size_t)(bn + sr) * K + gsw;
        u16* sA = lA + sr * 64 + sc;
        u16* sB = lB + sr * 64 + sc;
        const int nkt = K >> 6;
        for (int kt = 0; kt < nkt; ++kt) {
            __syncthreads();
            const u16* ga = gA + kt * 64;
            const u16* gb = gB + kt * 64;
            #pragma unroll
            for (int i = 0; i < 4; ++i)
                async_ld16(ga + (size_t)i * 32 * K, sA + i * 32 * 64);
            #pragma unroll
            for (int i = 0; i < 4; ++i)
                async_ld16(gb + (size_t)i * 32 * K, sB + i * 32 * 64);
            __syncthreads();
            #pragma unroll
            for (int ks = 0; ks < 2; ++ks) {
                bf16x8 af[4], bfr[4];
                #pragma unroll
                for (int i = 0; i < 4; ++i)
                    af[i] = *(const bf16x8*)(lA + (wr + i * 16 + lrow) * 64 +
                                             (((ks * 4 + lkq) ^ xr) << 3));
                #pragma unroll
                for (int i = 0; i < 4; ++i)
                    bfr[i] = *(const bf16x8*)(lB + (wc + i * 16 + lrow) * 64 +
                                              (((ks * 4 + lkq) ^ xr) << 3));
                #pragma unroll
                for (int mi = 0; mi < 4; ++mi)
                    #pragma unroll
                    for (int ni = 0; ni < 4; ++ni)
                        acc[mi][ni] = __builtin_amdgcn_mfma_f32_16x16x32_bf16(
                            af[mi], bfr[ni], acc[mi][ni], 0, 0, 0);
            }
        }
    }

    const int rbase = bm + wr + lkq * 4;
    const int cbase = bn + wc + lrow;
    if (BIAS_RELU) {
        #pragma unroll
        for (int ni = 0; ni < 4; ++ni) {
            const float bv = epi[cbase + ni * 16];
            #pragma unroll
            for (int mi = 0; mi < 4; ++mi)
                #pragma unroll
                for (int r = 0; r < 4; ++r) {
                    float v = acc[mi][ni][r] + bv;
                    v = fmaxf(v, 0.f);
                    C[(size_t)(rbase + mi * 16 + r) * N + cbase + ni * 16] = f2bf(v);
                }
        }
    } else {
        #pragma unroll
        for (int mi = 0; mi < 4; ++mi)
            #pragma unroll
            for (int r = 0; r < 4; ++r) {
                const float sv = epi[rbase + mi * 16 + r];
                #pragma unroll
                for (int ni = 0; ni < 4; ++ni)
                    C[(size_t)(rbase + mi * 16 + r) * N + cbase + ni * 16] =
                        f2bf(acc[mi][ni][r] * sv);
            }
    }
}

// ---------------- classifier GEMM (N=16) ----------------
__device__ __forceinline__ float bfdot2(u32 a, u32 b, float acc) {
    float al = __uint_as_float(a << 16), ah = __uint_as_float(a & 0xffff0000u);
    float bl = __uint_as_float(b << 16), bh = __uint_as_float(b & 0xffff0000u);
    return fmaf(ah, bh, fmaf(al, bl, acc));
}

__global__ __launch_bounds__(256) void gemm_cls(
    const u16* __restrict__ hc, const u16* __restrict__ Wc2,
    const float* __restrict__ bc2, float* __restrict__ out)
{
    const int c = threadIdx.x & 15;
    const int r = threadIdx.x >> 4;
    const int row = blockIdx.x * 16 + r;
    const uint4* hp = (const uint4*)(hc + (size_t)row * NP);
    const uint4* wp = (const uint4*)(Wc2 + (size_t)c * NP);
    float acc = 0.f;
    #pragma unroll 4
    for (int i = 0; i < NP / 8; ++i) {
        uint4 a = hp[i], b = wp[i];
        acc = bfdot2(a.x, b.x, acc);
        acc = bfdot2(a.y, b.y, acc);
        acc = bfdot2(a.z, b.z, acc);
        acc = bfdot2(a.w, b.w, acc);
    }
    out[(size_t)row * 16 + c] = acc + bc2[c];
}

// ---------------- launch ----------------

extern "C" void kernel_launch(void* const* d_in, const int* in_sizes, int n_in,
                              void* d_out, int out_size, void* d_ws, size_t ws_size,
                              hipStream_t stream) {
    const float* gene  = (const float*)d_in[0];
    const float* train = (const float*)d_in[1];
    const int*   esrc  = (const int*)d_in[2];
    const int*   edst  = (const int*)d_in[3];
    const float* W1s   = (const float*)d_in[4];
    const float* W1n   = (const float*)d_in[5];
    const float* b1    = (const float*)d_in[6];
    const float* W2s   = (const float*)d_in[7];
    const float* W2n   = (const float*)d_in[8];
    const float* b2    = (const float*)d_in[9];
    const float* Wc1   = (const float*)d_in[10];
    const float* bc1   = (const float*)d_in[11];
    const float* Wc2   = (const float*)d_in[12];
    const float* bc2   = (const float*)d_in[13];
    const int E = in_sizes[2];

    char* ws = (char*)d_ws;
    const size_t o_acnt  = 0;                       // u32 counts [M,NP]   (later: h)
    const size_t o_acntb = 167772160;               // bf16 counts         (later: h2)
    const size_t o_mean  = 251658240;               // bf16 mean_src       (later: hc)
    const size_t o_train = 335544320;               // bf16 train [M,K1P]
    const size_t o_w1s   = 423624704;               // [NP,K1P]
    const size_t o_w1n   = 437387264;               // [NP,NP]
    const size_t o_w2s   = 450494464;
    const size_t o_w2n   = 463601664;
    const size_t o_wc1   = 476708864;
    const size_t o_gft   = 489816064;               // gene_feat^T bf16 [NP,NP]
    const size_t o_wc2   = 502923264;               // [16,NP]
    const size_t o_b1    = 503005184;
    const size_t o_b2    = 503015424;
    const size_t o_bc1   = 503025664;
    const size_t o_rdeg  = 503035904;
    const size_t o_hist  = 503103488;               // u32 [MROWS]
    // end ~503.2 MB

    u32* ACNT   = (u32*)(ws + o_acnt);
    u16* ACNTB  = (u16*)(ws + o_acntb);
    u16* MEAN   = (u16*)(ws + o_mean);
    u16* TRAINB = (u16*)(ws + o_train);
    u16* W1S    = (u16*)(ws + o_w1s);
    u16* W1N    = (u16*)(ws + o_w1n);
    u16* W2S    = (u16*)(ws + o_w2s);
    u16* W2N    = (u16*)(ws + o_w2n);
    u16* WC1    = (u16*)(ws + o_wc1);
    u16* GFT    = (u16*)(ws + o_gft);
    u16* WC2    = (u16*)(ws + o_wc2);
    float* B1   = (float*)(ws + o_b1);
    float* B2   = (float*)(ws + o_b2);
    float* BC1  = (float*)(ws + o_bc1);
    float* RDEG = (float*)(ws + o_rdeg);
    u32* HIST   = (u32*)(ws + o_hist);
    u16* H  = (u16*)(ws + o_acnt);      // alias: u32 counts dead after cvt_counts
    u16* H2 = (u16*)(ws + o_acntb);     // alias: bf16 counts dead after G1
    u16* HC = (u16*)(ws + o_mean);      // alias: mean dead after G3

    // 1. counts + degree histogram (standard u32 atomics)
    hipMemsetAsync(ACNT, 0, (size_t)MROWS * NP * 4, stream);
    hipMemsetAsync(HIST, 0, MROWS * 4, stream);
    build_counts_u32<<<(E + 255) / 256, 256, 0, stream>>>(esrc, edst, E, ACNT, HIST);
    rdeg_from_hist<<<MROWS / 256, 256, 0, stream>>>(HIST, RDEG);
    cvt_counts_v<<<(int)((size_t)MROWS * NP / 8 / 256), 256, 0, stream>>>(ACNT, ACNTB);

    // 2. conversions / padding
    cvt_pad_s<<<MROWS, 256, 0, stream>>>(train, TRAINB, MROWS, 2675, K1P);  // odd stride
    cvt_pad_s<<<NP, 256, 0, stream>>>(W1s, W1S, 2500, 2675, K1P);           // odd stride
    cvt_pad4<<<dim3(NP, 4), 256, 0, stream>>>(W1n, W2s, W2n, Wc1, W1N, W2S, W2N, WC1);
    cvt_pad_wc2<<<16, 256, 0, stream>>>(Wc2, WC2);
    transpose_cvt<<<dim3(NP / 64, NP / 64), 256, 0, stream>>>(gene, GFT);
    pad_vec3<<<(3 * NP + 255) / 256, 256, 0, stream>>>(b1, b2, bc1, B1, B2, BC1);

    const dim3 ggrid(NP / 128, MROWS / 128);
    // 3. G1: mean_src = (A @ gene_feat) * rdeg   [bf16 out]
    gemm_bt<false, false><<<ggrid, 256, 0, stream>>>(
        ACNTB, GFT, NP, nullptr, nullptr, 0, RDEG, MEAN, NP);
    // 4. G2: h = relu(train @ W1s^T + mean @ W1n^T + b1)
    gemm_bt<true, true><<<ggrid, 256, 0, stream>>>(
        TRAINB, W1S, K1P, MEAN, W1N, NP, B1, H, NP);
    // 5. G3: h2 = relu(h @ W2s^T + mean @ W2n^T + b2)
    gemm_bt<true, true><<<ggrid, 256, 0, stream>>>(
        H, W2S, NP, MEAN, W2N, NP, B2, H2, NP);
    // 6. G4: hc = relu(h2 @ Wc1^T + bc1)
    gemm_bt<false, true><<<ggrid, 256, 0, stream>>>(
        H2, WC1, NP, nullptr, nullptr, 0, BC1, HC, NP);
    // 7. G5: out = hc @ Wc2^T + bc2
    gemm_cls<<<MROWS / 16, 256, 0, stream>>>(HC, WC2, bc2, (float*)d_out);
}